// Round 11
// baseline (7237.879 us; speedup 1.0000x reference)
//
#include <hip/hip_runtime.h>
#include <math.h>

// Sizes from the reference
#define SEQ   1024
#define DX    620      // EMB 300 + CHAR_ENC 128 + 3*POS_SZ 192
#define BIH   128
#define TLH   256
#define NTAGS 16

// ws layout (float offsets)
#define O_X      0
#define O_XGF    634880              // 1024*620
#define O_XGB    (O_XGF + 524288)    // 1024*512
#define O_XIOU   (O_XGB + 524288)
#define O_XF     (O_XIOU + 786432)   // 1024*768
#define O_LCNN   (O_XF + 262400)     // 1025*256
#define O_SCNN   (O_LCNN + 131072)   // 1024*128
#define O_PART   (O_SCNN + 262144)   // partials for gmax (16*256)
#define O_GCNN   (O_PART + 4096)     // 256
#define O_HF     (O_GCNN + 256)
#define O_HB     (O_HF + 131072)
#define O_TREEH  (O_HB + 131072)
#define O_IOUA   (O_TREEH + 262144)  // 1024*256
#define O_FCSUM  (O_IOUA + 787200)   // 1025*768
#define O_EMIS   (O_FCSUM + 262400)  // 1025*256
#define O_CNT    (O_EMIS + 16384)    // 64 ints: per-(class,rowgroup) tile counters

#define SENT 0xFFFFFFFFu

__device__ __forceinline__ float sig_f(float x){ return 1.0f/(1.0f + __expf(-x)); }
__device__ __forceinline__ float tanh_f(float x){
  float ax = fabsf(x);
  float e  = __expf(-2.0f*ax);
  float t  = (1.0f - e)/(1.0f + e);
  return x < 0.0f ? -t : t;
}
// XOR swizzle for 64-slot float4 h-buffer: spreads row-groups across banks
__device__ __forceinline__ int physslot(int s){ return s ^ ((s>>3)&7); }

// ---------------- embeddings + char conv ----------------
__global__ __launch_bounds__(128) void k_embed(
    const int* __restrict__ wi, const int* __restrict__ ci,
    const int* __restrict__ postag_in, const int* __restrict__ dep_in, const int* __restrict__ pos_in,
    const float* __restrict__ word_table, const float* __restrict__ char_table,
    const float* __restrict__ ccw, const float* __restrict__ ccb,
    const float* __restrict__ postag_table, const float* __restrict__ position_table,
    float* __restrict__ x)
{
  int s = blockIdx.x;
  int tid = threadIdx.x;
  __shared__ __align__(16) float ce[50][16];   // [ic][t]
  for (int idx = tid; idx < 800; idx += 128){
    int e = idx >> 4, t = idx & 15;
    ce[e][t] = char_table[ci[s*16 + t]*50 + e];
  }
  __syncthreads();
  float* xr = x + (size_t)s*DX;
  const float* wrow = word_table + (size_t)wi[s]*300;
  for (int d = tid; d < 300; d += 128) xr[d] = wrow[d];
  {
    int oc = tid; // 128
    const float* wp = ccw + oc*150;
    float acc[16];
    float b = ccb[oc];
    #pragma unroll
    for (int t=0;t<16;t++) acc[t] = b;
    for (int ic=0; ic<50; ic++){
      float w0 = wp[ic*3+0], w1 = wp[ic*3+1], w2 = wp[ic*3+2];
      float cv[16];
      float4 c0 = *(const float4*)&ce[ic][0];
      float4 c1 = *(const float4*)&ce[ic][4];
      float4 c2 = *(const float4*)&ce[ic][8];
      float4 c3 = *(const float4*)&ce[ic][12];
      cv[0]=c0.x;cv[1]=c0.y;cv[2]=c0.z;cv[3]=c0.w;
      cv[4]=c1.x;cv[5]=c1.y;cv[6]=c1.z;cv[7]=c1.w;
      cv[8]=c2.x;cv[9]=c2.y;cv[10]=c2.z;cv[11]=c2.w;
      cv[12]=c3.x;cv[13]=c3.y;cv[14]=c3.z;cv[15]=c3.w;
      #pragma unroll
      for (int t=0;t<16;t++){
        float a = cv[t]*w1;
        if (t > 0)  a += cv[t-1]*w0;
        if (t < 15) a += cv[t+1]*w2;
        acc[t] += a;
      }
    }
    float m = acc[0];
    #pragma unroll
    for (int t=1;t<16;t++) m = fmaxf(m, acc[t]);
    xr[300 + oc] = fmaxf(m, 0.0f);
  }
  if (tid < 64){
    int d = tid;
    xr[428 + d] = postag_table[postag_in[s]*64 + d];
    xr[492 + d] = position_table[pos_in[s]*64 + d];
    xr[556 + d] = position_table[dep_in[s]*64 + d];
  }
}

// ---------------- fp32 GEMM tile body ----------------
// agentc=1: C stored with agent-scope stores (cross-XCD visible within kernel)
__device__ __forceinline__ void gemm_tile(
    const float* __restrict__ x, const float* __restrict__ Bm,
    const float* __restrict__ bias, float* __restrict__ C,
    int N, int K, int amode, int bx, int by, int tid,
    float (*As)[64], float (*Bs)[64], int agentc)
{
  int bn = bx*64, bm = by*64;
  int lane = tid & 63, kg = tid >> 6;     // kg 0..3, each loads 5 k
  int tx = tid & 15, ty = tid >> 4;       // 16x16, micro 4x4
  float acc[4][4] = {{0.f}};
  for (int k0 = 0; k0 < K; k0 += 20){
    #pragma unroll
    for (int kk=0; kk<5; kk++){
      int k = kg*5 + kk;
      float av;
      if (amode == 0){
        av = x[(size_t)(bm+lane)*DX + k0 + k];
      } else {
        int kc = k0 + k;
        int d  = kc/3;
        int sh = kc - d*3 - 1;
        int row = bm + lane + sh;
        av = (row >= 0 && row < SEQ) ? x[(size_t)row*DX + d] : 0.0f;
      }
      As[k][lane] = av;
      Bs[k][lane] = (amode==0) ? Bm[(size_t)(k0+k)*N + bn + lane]
                               : Bm[(size_t)(bn+lane)*K + k0 + k];
    }
    __syncthreads();
    #pragma unroll
    for (int k=0;k<20;k++){
      float4 a = *(const float4*)&As[k][ty<<2];
      float4 b = *(const float4*)&Bs[k][tx<<2];
      acc[0][0]+=a.x*b.x; acc[0][1]+=a.x*b.y; acc[0][2]+=a.x*b.z; acc[0][3]+=a.x*b.w;
      acc[1][0]+=a.y*b.x; acc[1][1]+=a.y*b.y; acc[1][2]+=a.y*b.z; acc[1][3]+=a.y*b.w;
      acc[2][0]+=a.z*b.x; acc[2][1]+=a.z*b.y; acc[2][2]+=a.z*b.z; acc[2][3]+=a.z*b.w;
      acc[3][0]+=a.w*b.x; acc[3][1]+=a.w*b.y; acc[3][2]+=a.w*b.z; acc[3][3]+=a.w*b.w;
    }
    __syncthreads();
  }
  float4 bb;
  bb.x = bias[bn+(tx<<2)+0]; bb.y = bias[bn+(tx<<2)+1];
  bb.z = bias[bn+(tx<<2)+2]; bb.w = bias[bn+(tx<<2)+3];
  #pragma unroll
  for (int i=0;i<4;i++){
    int row = bm + (ty<<2) + i;
    float v0 = acc[i][0]+bb.x, v1 = acc[i][1]+bb.y, v2 = acc[i][2]+bb.z, v3 = acc[i][3]+bb.w;
    if (agentc){
      float* p = &C[(size_t)row*N + bn + (tx<<2)];
      __hip_atomic_store(p+0, v0, __ATOMIC_RELAXED, __HIP_MEMORY_SCOPE_AGENT);
      __hip_atomic_store(p+1, v1, __ATOMIC_RELAXED, __HIP_MEMORY_SCOPE_AGENT);
      __hip_atomic_store(p+2, v2, __ATOMIC_RELAXED, __HIP_MEMORY_SCOPE_AGENT);
      __hip_atomic_store(p+3, v3, __ATOMIC_RELAXED, __HIP_MEMORY_SCOPE_AGENT);
    } else {
      float4 o; o.x=v0; o.y=v1; o.z=v2; o.w=v3;
      *(float4*)&C[(size_t)row*N + bn + (tx<<2)] = o;
    }
  }
}

// ---------------- global max over tokens for sent conv (two-stage) --------
__global__ __launch_bounds__(256) void k_gmax1(const float* __restrict__ scnn, float* __restrict__ part){
  int b = blockIdx.x, c = threadIdx.x;
  float m = -3.0e38f;
  for (int s = b*64; s < b*64 + 64; s++) m = fmaxf(m, scnn[(size_t)s*256 + c]);
  part[b*256 + c] = m;
}
__global__ __launch_bounds__(256) void k_gmax2(const float* __restrict__ part, float* __restrict__ gcnn){
  int c = threadIdx.x;
  float m = -3.0e38f;
  for (int b=0; b<16; b++) m = fmaxf(m, part[b*256 + c]);
  gcnn[c] = m;
}

struct RGemm {
  const float* B[4];
  const float* bias[4];
  float*       C[4];
  int          N[4];
};

// ---------------- persistent recurrent kernel + ALL folded GEMMs ----------
// 294 blocks x 256 threads (all co-resident: VGPR<=256 via (256,2) -> >=2
// blocks/CU -> 512 capacity):
//   bid 0..3    tree-LSTM slices (LLC dataflow exchange)
//   bid 4,5     fwd/bwd LSTM
//   bid 6..261  input GEMM workers: 2 tiles each of {xg_f,xg_b,xiou,xf}
//               (z1 scheduled in REVERSE row order for the bwd LSTM);
//               C stored agent-scope; per-(class,rowgroup) counter released
//               after each tile. Consumers gate on counters via a watermark
//               (polls only at group boundaries; free in steady state).
//   bid 262..293 conv GEMM workers (3 tiles each, consumed post-kernel)
__global__ __launch_bounds__(256, 2) void k_recur(
    const float* __restrict__ xg_f, const float* __restrict__ xg_b,
    const float* __restrict__ Wh_f, const float* __restrict__ Wh_b,
    const float* __restrict__ xiou, const float* __restrict__ xf,
    const float* __restrict__ Uiou, const float* __restrict__ Uf,
    const int* __restrict__ order, const int* __restrict__ parent,
    float* __restrict__ hf, float* __restrict__ hb,
    float* tree_h, float* iou_acc, float* fcsum,
    const float* __restrict__ x, RGemm rg_args,
    const float* __restrict__ wcnn_w, const float* __restrict__ wcnn_b,
    const float* __restrict__ scnn_w, const float* __restrict__ scnn_b,
    float* __restrict__ lcnn, float* __restrict__ scnn,
    int* cnt)
{
  int bid = blockIdx.x;
  int tid = threadIdx.x;

  if (bid >= 262){
    // ---------- conv GEMM tiles (im2row, K=1860): 3 tiles per block -------
    __shared__ __align__(16) float As[20][64];
    __shared__ __align__(16) float Bs[20][64];
    int j = bid - 262;
    for (int s=0;s<3;s++){
      int tn = j*3 + s;
      if (tn < 32) gemm_tile(x, wcnn_w, wcnn_b, lcnn, 128, 1860, 1, tn&1, tn>>1, tid, As, Bs, 0);
      else { int t2 = tn-32; gemm_tile(x, scnn_w, scnn_b, scnn, 256, 1860, 1, t2&3, t2>>2, tid, As, Bs, 0); }
      __syncthreads();
    }
    return;
  }

  if (bid >= 6){
    // ---------- input GEMM tiles (K=620): 2 tiles per block ----------
    __shared__ __align__(16) float As[20][64];
    __shared__ __align__(16) float Bs[20][64];
    int j = bid - 6;
    for (int s=0;s<2;s++){
      int T = j*2 + s;                 // 0..511, k-chunk ordered
      int k = T>>5, r = T&31;
      int z, by, bn;
      if (r < 8)       { z=0; by=k;    bn=r;    }
      else if (r < 16) { z=1; by=15-k; bn=r-8;  }   // bwd LSTM rows first
      else if (r < 28) { z=2; by=k;    bn=r-16; }
      else             { z=3; by=k;    bn=r-28; }
      gemm_tile(x, rg_args.B[z], rg_args.bias[z], rg_args.C[z], rg_args.N[z],
                620, 0, bn, by, tid, As, Bs, 1);
      __syncthreads();   // drain all waves' C stores (vmcnt before barrier)
      if (tid == 0)
        __hip_atomic_fetch_add(&cnt[z*16 + by], 1, __ATOMIC_RELEASE, __HIP_MEMORY_SCOPE_AGENT);
      __syncthreads();
    }
    return;
  }

  if (bid >= 4){
    // ---------- BiLSTM: thread = (colgrp 0..127, rowgrp 0..1) ----------
    const float* xg  = (bid == 4) ? xg_f : xg_b;
    const float* Wh  = (bid == 4) ? Wh_f : Wh_b;
    float* hout      = (bid == 4) ? hf : hb;
    int zc = (bid == 4) ? 0 : 1;
    int cg = tid >> 1, rg = tid & 1;          // 4 cols, 64 rows each
    float4 w[4][16];
    #pragma unroll
    for (int cc=0;cc<4;cc++){
      int col = cg*4 + cc;
      #pragma unroll
      for (int r4=0;r4<16;r4++){
        int row = rg*64 + r4*4;
        w[cc][r4].x = Wh[(size_t)(row+0)*512 + col];
        w[cc][r4].y = Wh[(size_t)(row+1)*512 + col];
        w[cc][r4].z = Wh[(size_t)(row+2)*512 + col];
        w[cc][r4].w = Wh[(size_t)(row+3)*512 + col];
      }
    }
    #pragma unroll
    for (int cc=0;cc<4;cc++)
      #pragma unroll
      for (int r4=0;r4<16;r4++)
        asm volatile("" : "+v"(w[cc][r4].x), "+v"(w[cc][r4].y), "+v"(w[cc][r4].z), "+v"(w[cc][r4].w));

    __shared__ __align__(16) float lhl[BIH];
    __shared__ float lcst[BIH];
    __shared__ float gl[512];
    if (tid < BIH){ lhl[tid] = 0.f; lcst[tid] = 0.f; }
    __syncthreads();
    const float4* lhl4 = (const float4*)lhl;

    // watermark over xg row-groups (fwd ascending, bwd descending)
    int Wm = (bid == 4) ? -1 : 16;
    {
      int n0 = (bid == 4) ? 0 : (SEQ-1);
      int g0 = n0 >> 6;
      if (bid == 4){
        for (int g = Wm+1; g <= g0; g++)
          while (__hip_atomic_load(&cnt[zc*16+g], __ATOMIC_ACQUIRE, __HIP_MEMORY_SCOPE_AGENT) < 8)
            __builtin_amdgcn_s_sleep(8);
      } else {
        for (int g = Wm-1; g >= g0; g--)
          while (__hip_atomic_load(&cnt[zc*16+g], __ATOMIC_ACQUIRE, __HIP_MEMORY_SCOPE_AGENT) < 8)
            __builtin_amdgcn_s_sleep(8);
      }
      Wm = g0;
    }
    float4 nxg4 = make_float4(0.f,0.f,0.f,0.f);
    if (rg == 0){
      int n0 = (bid == 4) ? 0 : (SEQ-1);
      nxg4 = *(const float4*)&xg[(size_t)n0*512 + cg*4];
    }
    for (int st=0; st<SEQ; st++){
      int n = (bid == 4) ? st : (SEQ-1-st);
      float4 xg4 = nxg4;
      if (st+1 < SEQ){
        int n1 = (bid == 4) ? (st+1) : (SEQ-2-st);
        int g1 = n1 >> 6;
        if (bid == 4){
          if (g1 > Wm){
            for (int g = Wm+1; g <= g1; g++)
              while (__hip_atomic_load(&cnt[zc*16+g], __ATOMIC_ACQUIRE, __HIP_MEMORY_SCOPE_AGENT) < 8)
                __builtin_amdgcn_s_sleep(8);
            Wm = g1;
          }
        } else {
          if (g1 < Wm){
            for (int g = Wm-1; g >= g1; g--)
              while (__hip_atomic_load(&cnt[zc*16+g], __ATOMIC_ACQUIRE, __HIP_MEMORY_SCOPE_AGENT) < 8)
                __builtin_amdgcn_s_sleep(8);
            Wm = g1;
          }
        }
        if (rg == 0) nxg4 = *(const float4*)&xg[(size_t)n1*512 + cg*4];
      }
      float acc[4] = {0.f,0.f,0.f,0.f};
      #pragma unroll
      for (int r4=0;r4<16;r4++){
        float4 h4 = lhl4[rg*16 + r4];
        #pragma unroll
        for (int cc=0;cc<4;cc++)
          acc[cc] += h4.x*w[cc][r4].x + h4.y*w[cc][r4].y + h4.z*w[cc][r4].z + h4.w*w[cc][r4].w;
      }
      #pragma unroll
      for (int cc=0;cc<4;cc++) acc[cc] += __shfl_xor(acc[cc], 1);
      if (rg == 0){
        float4 o = make_float4(acc[0]+xg4.x, acc[1]+xg4.y, acc[2]+xg4.z, acc[3]+xg4.w);
        *(float4*)&gl[cg*4] = o;
      }
      __syncthreads();   // B1: gates ready
      if (tid < BIH){
        float gi = gl[tid], gf = gl[BIH+tid], gg = gl[2*BIH+tid], go = gl[3*BIH+tid];
        float c = sig_f(gf)*lcst[tid] + sig_f(gi)*tanh_f(gg);
        float h = sig_f(go)*tanh_f(c);
        lcst[tid] = c;
        lhl[tid] = h;
        hout[(size_t)n*BIH + tid] = h;
      }
      __syncthreads();   // B2: lhl ready for next step
    }
    return;
  }

  // ---------- tree-LSTM: 64 units per block ----------
  int blk = bid;
  int cg = tid >> 3, rg = tid & 7;
  int ulo = blk*64;
  float4 w[8][8];   // w[cc][r4]: col cg*8+cc, rows rg*32 + 4*r4 ..+3
  #pragma unroll
  for (int cc=0;cc<8;cc++){
    int c = cg*8 + cc;
    const float* Wsrc; size_t stride; int gcol;
    if (c < 192){ Wsrc = Uiou; stride = 768; gcol = (c>>6)*TLH + ulo + (c&63); }
    else        { Wsrc = Uf;   stride = 256; gcol = ulo + (c-192); }
    #pragma unroll
    for (int r4=0;r4<8;r4++){
      int row = rg*32 + r4*4;
      w[cc][r4].x = Wsrc[(size_t)(row+0)*stride + gcol];
      w[cc][r4].y = Wsrc[(size_t)(row+1)*stride + gcol];
      w[cc][r4].z = Wsrc[(size_t)(row+2)*stride + gcol];
      w[cc][r4].w = Wsrc[(size_t)(row+3)*stride + gcol];
    }
  }
  #pragma unroll
  for (int cc=0;cc<8;cc++)
    #pragma unroll
    for (int r4=0;r4<8;r4++)
      asm volatile("" : "+v"(w[cc][r4].x), "+v"(w[cc][r4].y), "+v"(w[cc][r4].z), "+v"(w[cc][r4].w));

  __shared__ __align__(16) float hl[TLH];      // XOR-swizzled float4 slots
  __shared__ float colsum[TLH];
  __shared__ float cprev[64];
  __shared__ int ord_l[SEQ];
  __shared__ int par_l[SEQ];
  for (int i=tid; i<SEQ; i+=256){ ord_l[i] = order[i]; par_l[i] = parent[i]; }
  __syncthreads();
  const float4* hl4 = (const float4*)hl;

  // watermark over xiou (z2, 12 tiles/group) and xf (z3, 4 tiles/group)
  int Wm = -1;
  float nxi=0.f, nxo=0.f, nxu=0.f, nxf=0.f;
  if (tid < 64){
    int n0 = ord_l[0];
    int need = n0 >> 6;
    for (int g = 0; g <= need; g++){
      while (__hip_atomic_load(&cnt[32+g], __ATOMIC_ACQUIRE, __HIP_MEMORY_SCOPE_AGENT) < 12)
        __builtin_amdgcn_s_sleep(8);
      while (__hip_atomic_load(&cnt[48+g], __ATOMIC_ACQUIRE, __HIP_MEMORY_SCOPE_AGENT) < 4)
        __builtin_amdgcn_s_sleep(8);
    }
    Wm = need;
    int uu = ulo + tid;
    nxi = xiou[(size_t)n0*768 + uu];
    nxo = xiou[(size_t)n0*768 + 256 + uu];
    nxu = xiou[(size_t)n0*768 + 512 + uu];
  }

  for (int t=0; t<SEQ; t++){
    int n  = ord_l[t];
    int m  = (t > 0) ? ord_l[t-1] : 0;
    int pp = (t > 0) ? par_l[m] : -1;
    bool ppeq = (pp == n);

    // consume prefetched x rows; issue next step's prefetch; load accumulators
    float xi=nxi, xo=nxo, xu=nxu, xfv=nxf;
    float ac_i=0.f, ac_o=0.f, ac_u=0.f, fcn=0.f;
    float po_i=0.f, po_o=0.f, po_u=0.f, po_f=0.f;
    if (tid < 64){
      int uu = ulo + tid;
      if (t+1 < SEQ){
        int n1 = ord_l[t+1];
        int pr = par_l[n];                 // pp(t+1) = parent(n)
        int need = n1 >> 6;
        if (pr < SEQ && (pr>>6) > need) need = pr>>6;
        if (need > Wm){
          for (int g = Wm+1; g <= need; g++){
            while (__hip_atomic_load(&cnt[32+g], __ATOMIC_ACQUIRE, __HIP_MEMORY_SCOPE_AGENT) < 12)
              __builtin_amdgcn_s_sleep(8);
            while (__hip_atomic_load(&cnt[48+g], __ATOMIC_ACQUIRE, __HIP_MEMORY_SCOPE_AGENT) < 4)
              __builtin_amdgcn_s_sleep(8);
          }
          Wm = need;
        }
        nxi = xiou[(size_t)n1*768 + uu];
        nxo = xiou[(size_t)n1*768 + 256 + uu];
        nxu = xiou[(size_t)n1*768 + 512 + uu];
        nxf = xf[(size_t)pr*256 + uu];
      }
      ac_i = iou_acc[(size_t)n*768 + uu];
      ac_o = iou_acc[(size_t)n*768 + 256 + uu];
      ac_u = iou_acc[(size_t)n*768 + 512 + uu];
      fcn  = fcsum[(size_t)n*256 + uu];
      if (t > 0 && !ppeq){
        po_i = iou_acc[(size_t)pp*768 + uu];
        po_o = iou_acc[(size_t)pp*768 + 256 + uu];
        po_u = iou_acc[(size_t)pp*768 + 512 + uu];
        po_f = fcsum[(size_t)pp*256 + uu];
      }
    }

    // matvec over h(prev node): 8 swizzled b128 reads, 256 FMAs, shfl reduce
    if (t > 0){
      float acc[8] = {0.f,0.f,0.f,0.f,0.f,0.f,0.f,0.f};
      int base = rg << 3;
      #pragma unroll
      for (int r4=0;r4<8;r4++){
        float4 h4 = hl4[base + (r4 ^ rg)];
        #pragma unroll
        for (int cc=0;cc<8;cc++)
          acc[cc] += h4.x*w[cc][r4].x + h4.y*w[cc][r4].y + h4.z*w[cc][r4].z + h4.w*w[cc][r4].w;
      }
      #pragma unroll
      for (int cc=0;cc<8;cc++){
        acc[cc] += __shfl_xor(acc[cc], 1);
        acc[cc] += __shfl_xor(acc[cc], 2);
        acc[cc] += __shfl_xor(acc[cc], 4);
      }
      if (rg == 0){
        *(float4*)&colsum[cg*8]     = make_float4(acc[0], acc[1], acc[2], acc[3]);
        *(float4*)&colsum[cg*8 + 4] = make_float4(acc[4], acc[5], acc[6], acc[7]);
      }
    }
    __syncthreads();   // B1: colsum ready

    if (tid < 64){
      // fused accumulator-update + cell for unit ulo+tid; publish h (AGENT)
      int uu = ulo + tid;
      float ai = ac_i, ao = ac_o, au = ac_u, fcs = fcn;
      if (t > 0){
        float vi = colsum[tid], vo = colsum[64+tid], vuu = colsum[128+tid], vf = colsum[192+tid];
        float fg  = sig_f(xfv + vf);
        float fcc = fg * cprev[tid];
        if (ppeq){
          ai += vi; ao += vo; au += vuu; fcs += fcc;
        } else {
          iou_acc[(size_t)pp*768 + uu]       = po_i + vi;
          iou_acc[(size_t)pp*768 + 256 + uu] = po_o + vo;
          iou_acc[(size_t)pp*768 + 512 + uu] = po_u + vuu;
          fcsum[(size_t)pp*256 + uu]         = po_f + fcc;
        }
      }
      float cc = sig_f(xi + ai)*tanh_f(xu + au) + fcs;
      float hh = sig_f(xo + ao)*tanh_f(cc);
      cprev[tid] = cc;
      int s = uu >> 2;
      hl[physslot(s)*4 + (uu & 3)] = hh;
      __hip_atomic_store(&tree_h[(size_t)n*TLH + uu], hh, __ATOMIC_RELAXED, __HIP_MEMORY_SCOPE_AGENT);
    } else {
      // gather foreign 192 floats: 192 PARALLEL single-dword AGENT pollers
      int p  = tid - 64;
      int fi = (p < ulo) ? p : p + 64;   // skip own 64 units
      const unsigned* tp = (const unsigned*)(tree_h + (size_t)n*TLH + fi);
      unsigned v = __hip_atomic_load(tp, __ATOMIC_RELAXED, __HIP_MEMORY_SCOPE_AGENT);
      while (v == SENT){
        __builtin_amdgcn_s_sleep(1);
        v = __hip_atomic_load(tp, __ATOMIC_RELAXED, __HIP_MEMORY_SCOPE_AGENT);
      }
      hl[physslot(fi>>2)*4 + (fi&3)] = __uint_as_float(v);
    }
    __syncthreads();   // B2: hl(n) complete for next step's matvec
  }
}

// ---------------- assemble SE + emissions + relations ----------------
__global__ __launch_bounds__(256) void k_assemble(
    const float* __restrict__ hf, const float* __restrict__ hb,
    const float* __restrict__ lcnn, const float* __restrict__ tree_h,
    const float* __restrict__ gcnn,
    const float* __restrict__ crf_w, const float* __restrict__ crf_b,
    const float* __restrict__ rel_w, const float* __restrict__ rel_b,
    const int* __restrict__ ptk,
    float* __restrict__ se_out, float* __restrict__ emis, float* __restrict__ rel_out)
{
  int s = blockIdx.x, tid = threadIdx.x;
  int p = ptk[0];
  __shared__ float se[1536];
  for (int d = tid; d < 1536; d += 256){
    float v;
    if      (d < 128)  v = hf[(size_t)s*128 + d];
    else if (d < 256)  v = hb[(size_t)s*128 + d-128];
    else if (d < 384)  v = lcnn[(size_t)s*128 + d-256];
    else if (d < 640)  v = tree_h[(size_t)s*256 + d-384];
    else if (d < 768)  v = hf[(size_t)p*128 + d-640];
    else if (d < 896)  v = hb[(size_t)p*128 + d-768];
    else if (d < 1024) v = lcnn[(size_t)p*128 + d-896];
    else if (d < 1280) v = tree_h[(size_t)p*256 + d-1024];
    else               v = gcnn[d-1280];
    se[d] = v;
    se_out[(size_t)s*1536 + d] = v;
  }
  __syncthreads();
  int o = tid >> 3, l = tid & 7;   // 32 outputs x 8 lanes
  const float* W = (o < 16) ? crf_w : rel_w;
  int oc = (o < 16) ? o : (o - 16);
  float a = 0.f;
  for (int k = l; k < 1536; k += 8) a += se[k]*W[(size_t)k*16 + oc];
  for (int off = 4; off; off >>= 1) a += __shfl_down(a, off, 8);
  if (l == 0){
    if (o < 16) emis[(size_t)s*16 + o] = a + crf_b[o];
    else        rel_out[(size_t)s*16 + oc] = sig_f(a + rel_b[oc]);
  }
}

// ---------------- entity type ----------------
__global__ __launch_bounds__(256) void k_entity(
    const float* __restrict__ hf, const float* __restrict__ hb,
    const float* __restrict__ lcnn, const float* __restrict__ tree_h,
    const float* __restrict__ gcnn,
    const float* __restrict__ et_w, const float* __restrict__ et_b,
    const int* __restrict__ ptk, float* __restrict__ out_et)
{
  __shared__ float ov[896];
  __shared__ float lg[8];
  int tid = threadIdx.x;
  int p = ptk[0];
  for (int d = tid; d < 896; d += 256){
    float v;
    if      (d < 256) v = gcnn[d];
    else if (d < 384) v = hf[(size_t)p*128 + d-256];
    else if (d < 512) v = hb[(size_t)p*128 + d-384];
    else if (d < 640) v = lcnn[(size_t)p*128 + d-512];
    else              v = tree_h[(size_t)p*256 + d-640];
    ov[d] = v;
  }
  __syncthreads();
  int o = tid >> 5, l = tid & 31;
  float a = 0.f;
  for (int k = l; k < 896; k += 32) a += ov[k]*et_w[(size_t)k*8 + o];
  for (int off = 16; off; off >>= 1) a += __shfl_down(a, off, 32);
  if (l == 0) lg[o] = a + et_b[o];
  __syncthreads();
  if (tid == 0){
    float mx = lg[0];
    for (int i=1;i<8;i++) mx = fmaxf(mx, lg[i]);
    float e[8], sum = 0.f;
    for (int i=0;i<8;i++){ e[i] = __expf(lg[i]-mx); sum += e[i]; }
    for (int i=0;i<8;i++) out_et[i] = e[i]/sum;
  }
}

// ---------------- viterbi: single wave, barrier-free ----------------
__global__ __launch_bounds__(64) void k_viterbi(
    const float* __restrict__ emis, const float* __restrict__ trans, float* __restrict__ out_e)
{
  __shared__ __align__(16) float ring[64][16];
  __shared__ unsigned char ptrs[1023*16];
  __shared__ float scL[16];
  int l = threadIdx.x;
  int j = l >> 2, iq = l & 3;
  float tr0 = trans[(iq*4+0)*16 + j];
  float tr1 = trans[(iq*4+1)*16 + j];
  float tr2 = trans[(iq*4+2)*16 + j];
  float tr3 = trans[(iq*4+3)*16 + j];
  {
    const float* src = &emis[(size_t)l*16];
    float4 a = *(const float4*)(src+0), b = *(const float4*)(src+4);
    float4 c = *(const float4*)(src+8), d = *(const float4*)(src+12);
    *(float4*)&ring[l][0] = a;  *(float4*)&ring[l][4] = b;
    *(float4*)&ring[l][8] = c;  *(float4*)&ring[l][12] = d;
  }
  float cur = ring[0][j];
  float sc0 = __shfl(cur, (iq*4+0)<<2, 64);
  float sc1 = __shfl(cur, (iq*4+1)<<2, 64);
  float sc2 = __shfl(cur, (iq*4+2)<<2, 64);
  float sc3 = __shfl(cur, (iq*4+3)<<2, 64);
  float myfinal = cur;
  for (int t=1; t<1024; t++){
    if ((t & 63) == 0){
      const float* src = &emis[(size_t)(t+l)*16];
      float4 a = *(const float4*)(src+0), b = *(const float4*)(src+4);
      float4 c = *(const float4*)(src+8), d = *(const float4*)(src+12);
      int rr = (t+l) & 63;
      *(float4*)&ring[rr][0] = a;  *(float4*)&ring[rr][4] = b;
      *(float4*)&ring[rr][8] = c;  *(float4*)&ring[rr][12] = d;
    }
    float v0 = sc0 + tr0, v1 = sc1 + tr1, v2 = sc2 + tr2, v3 = sc3 + tr3;
    float best = v0; int barg = iq*4;
    if (v1 > best){ best = v1; barg = iq*4+1; }
    if (v2 > best){ best = v2; barg = iq*4+2; }
    if (v3 > best){ best = v3; barg = iq*4+3; }
    float ob = __shfl_down(best, 1, 4); int oa = __shfl_down(barg, 1, 4);
    if (ob > best){ best = ob; barg = oa; }
    ob = __shfl_down(best, 2, 4); oa = __shfl_down(barg, 2, 4);
    if (ob > best){ best = ob; barg = oa; }
    float ns = 0.f;
    if (iq == 0){
      ns = best + ring[t & 63][j];
      ptrs[(t-1)*16 + j] = (unsigned char)barg;
      myfinal = ns;
    }
    sc0 = __shfl(ns, (iq*4+0)<<2, 64);
    sc1 = __shfl(ns, (iq*4+1)<<2, 64);
    sc2 = __shfl(ns, (iq*4+2)<<2, 64);
    sc3 = __shfl(ns, (iq*4+3)<<2, 64);
  }
  if (iq == 0) scL[j] = myfinal;
  if (l == 0){
    float b = scL[0]; int last = 0;
    #pragma unroll
    for (int i=1;i<16;i++){ if (scL[i] > b){ b = scL[i]; last = i; } }
    out_e[1023] = (float)last;
    int cur2 = last;
    for (int t=1022; t>=0; t--){ cur2 = (int)ptrs[t*16 + cur2]; out_e[t] = (float)cur2; }
  }
}

extern "C" void kernel_launch(void* const* d_in, const int* in_sizes, int n_in,
                              void* d_out, int out_size, void* d_ws, size_t ws_size,
                              hipStream_t stream)
{
  (void)in_sizes; (void)n_in; (void)out_size; (void)ws_size;
  const int*   wi         = (const int*)d_in[0];
  const int*   ci         = (const int*)d_in[1];
  const int*   postag_in  = (const int*)d_in[2];
  const int*   dep_in     = (const int*)d_in[3];
  const int*   pos_in     = (const int*)d_in[4];
  const int*   order      = (const int*)d_in[5];
  const int*   parent     = (const int*)d_in[6];
  const int*   ptk        = (const int*)d_in[7];
  const float* word_table = (const float*)d_in[8];
  const float* char_table = (const float*)d_in[9];
  const float* ccw        = (const float*)d_in[10];
  const float* ccb        = (const float*)d_in[11];
  const float* postag_tab = (const float*)d_in[12];
  const float* pos_tab    = (const float*)d_in[13];
  const float* Wx_f       = (const float*)d_in[14];
  const float* Wh_f       = (const float*)d_in[15];
  const float* b_f        = (const float*)d_in[16];
  const float* Wx_b       = (const float*)d_in[17];
  const float* Wh_b       = (const float*)d_in[18];
  const float* b_b        = (const float*)d_in[19];
  const float* wcnn_w     = (const float*)d_in[20];
  const float* wcnn_b     = (const float*)d_in[21];
  const float* Wiou       = (const float*)d_in[22];
  const float* Uiou       = (const float*)d_in[23];
  const float* biou       = (const float*)d_in[24];
  const float* Wf_t       = (const float*)d_in[25];
  const float* Uf_t       = (const float*)d_in[26];
  const float* bf_t       = (const float*)d_in[27];
  const float* scnn_w     = (const float*)d_in[28];
  const float* scnn_b     = (const float*)d_in[29];
  const float* et_w       = (const float*)d_in[30];
  const float* et_b       = (const float*)d_in[31];
  const float* crf_w      = (const float*)d_in[32];
  const float* crf_b      = (const float*)d_in[33];
  const float* crf_trans  = (const float*)d_in[34];
  const float* rel_w      = (const float*)d_in[35];
  const float* rel_b      = (const float*)d_in[36];

  float* ws = (float*)d_ws;
  float* x      = ws + O_X;
  float* xg_f   = ws + O_XGF;
  float* xg_b   = ws + O_XGB;
  float* xiou   = ws + O_XIOU;
  float* xf     = ws + O_XF;
  float* lcnn   = ws + O_LCNN;
  float* scnn   = ws + O_SCNN;
  float* part   = ws + O_PART;
  float* gcnn   = ws + O_GCNN;
  float* hf     = ws + O_HF;
  float* hb     = ws + O_HB;
  float* tree_h = ws + O_TREEH;
  float* iou_acc= ws + O_IOUA;
  float* fcsum  = ws + O_FCSUM;
  float* emis   = ws + O_EMIS;
  int*   cnt    = (int*)(ws + O_CNT);

  float* outF     = (float*)d_out;
  float* se_out   = outF;                       // 1024*1536
  float* et_out   = outF + 1572864;             // 8
  float* ent_out  = outF + 1572872;             // 1024
  float* rel_out  = outF + 1573896;             // 1024*16

  // per-launch init: zero accumulators + xf pad rows + counters; sentinel tree_h
  hipMemsetAsync(xf, 0, (size_t)1025*256*sizeof(float), stream);
  hipMemsetAsync(iou_acc, 0, ((size_t)1025*768 + 1025*256)*sizeof(float), stream);
  hipMemsetAsync(tree_h, 0xFF, (size_t)1024*256*sizeof(float), stream);
  hipMemsetAsync(cnt, 0, 256, stream);

  k_embed<<<SEQ, 128, 0, stream>>>(wi, ci, postag_in, dep_in, pos_in,
                                   word_table, char_table, ccw, ccb,
                                   postag_tab, pos_tab, x);

  RGemm rga;
  rga.B[0]=Wx_f;  rga.bias[0]=b_f;   rga.C[0]=xg_f; rga.N[0]=512;
  rga.B[1]=Wx_b;  rga.bias[1]=b_b;   rga.C[1]=xg_b; rga.N[1]=512;
  rga.B[2]=Wiou;  rga.bias[2]=biou;  rga.C[2]=xiou; rga.N[2]=768;
  rga.B[3]=Wf_t;  rga.bias[3]=bf_t;  rga.C[3]=xf;   rga.N[3]=256;

  // ALL GEMMs folded into k_recur (294 blocks, all co-resident)
  k_recur<<<294, 256, 0, stream>>>(xg_f, xg_b, Wh_f, Wh_b, xiou, xf, Uiou, Uf_t,
                                   order, parent, hf, hb, tree_h, iou_acc, fcsum,
                                   x, rga, wcnn_w, wcnn_b, scnn_w, scnn_b, lcnn, scnn,
                                   cnt);

  k_gmax1<<<16, 256, 0, stream>>>(scnn, part);
  k_gmax2<<<1, 256, 0, stream>>>(part, gcnn);

  k_assemble<<<SEQ, 256, 0, stream>>>(hf, hb, lcnn, tree_h, gcnn,
                                      crf_w, crf_b, rel_w, rel_b, ptk,
                                      se_out, emis, rel_out);

  k_entity<<<1, 256, 0, stream>>>(hf, hb, lcnn, tree_h, gcnn, et_w, et_b, ptk, et_out);

  k_viterbi<<<1, 64, 0, stream>>>(emis, crf_trans, ent_out);
}

// Round 12
// 2716.785 us; speedup vs baseline: 2.6641x; 2.6641x over previous
//
#include <hip/hip_runtime.h>
#include <math.h>

// Sizes from the reference
#define SEQ   1024
#define DX    620      // EMB 300 + CHAR_ENC 128 + 3*POS_SZ 192
#define BIH   128
#define TLH   256
#define NTAGS 16

// ws layout (float offsets)
#define O_X      0
#define O_XGF    634880              // 1024*620
#define O_XGB    (O_XGF + 524288)    // 1024*512
#define O_XIOU   (O_XGB + 524288)
#define O_XF     (O_XIOU + 786432)   // 1024*768
#define O_LCNN   (O_XF + 262400)     // 1025*256
#define O_SCNN   (O_LCNN + 131072)   // 1024*128
#define O_PART   (O_SCNN + 262144)   // partials for gmax (16*256)
#define O_GCNN   (O_PART + 4096)     // 256
#define O_HF     (O_GCNN + 256)
#define O_HB     (O_HF + 131072)
#define O_TREEH  (O_HB + 131072)
#define O_IOUA   (O_TREEH + 262144)  // 1024*256
#define O_FCSUM  (O_IOUA + 787200)   // 1025*768
#define O_EMIS   (O_FCSUM + 262400)  // 1025*256
#define O_CNT    (O_EMIS + 16384)    // 64 ints: per-(class,rowgroup) tile counters

#define SENT 0xFFFFFFFFu

__device__ __forceinline__ float sig_f(float x){ return 1.0f/(1.0f + __expf(-x)); }
__device__ __forceinline__ float tanh_f(float x){
  float ax = fabsf(x);
  float e  = __expf(-2.0f*ax);
  float t  = (1.0f - e)/(1.0f + e);
  return x < 0.0f ? -t : t;
}
// XOR swizzle for 64-slot float4 h-buffer: spreads row-groups across banks
__device__ __forceinline__ int physslot(int s){ return s ^ ((s>>3)&7); }

// ---------------- embeddings + char conv ----------------
__global__ __launch_bounds__(128) void k_embed(
    const int* __restrict__ wi, const int* __restrict__ ci,
    const int* __restrict__ postag_in, const int* __restrict__ dep_in, const int* __restrict__ pos_in,
    const float* __restrict__ word_table, const float* __restrict__ char_table,
    const float* __restrict__ ccw, const float* __restrict__ ccb,
    const float* __restrict__ postag_table, const float* __restrict__ position_table,
    float* __restrict__ x)
{
  int s = blockIdx.x;
  int tid = threadIdx.x;
  __shared__ __align__(16) float ce[50][16];   // [ic][t]
  for (int idx = tid; idx < 800; idx += 128){
    int e = idx >> 4, t = idx & 15;
    ce[e][t] = char_table[ci[s*16 + t]*50 + e];
  }
  __syncthreads();
  float* xr = x + (size_t)s*DX;
  const float* wrow = word_table + (size_t)wi[s]*300;
  for (int d = tid; d < 300; d += 128) xr[d] = wrow[d];
  {
    int oc = tid; // 128
    const float* wp = ccw + oc*150;
    float acc[16];
    float b = ccb[oc];
    #pragma unroll
    for (int t=0;t<16;t++) acc[t] = b;
    for (int ic=0; ic<50; ic++){
      float w0 = wp[ic*3+0], w1 = wp[ic*3+1], w2 = wp[ic*3+2];
      float cv[16];
      float4 c0 = *(const float4*)&ce[ic][0];
      float4 c1 = *(const float4*)&ce[ic][4];
      float4 c2 = *(const float4*)&ce[ic][8];
      float4 c3 = *(const float4*)&ce[ic][12];
      cv[0]=c0.x;cv[1]=c0.y;cv[2]=c0.z;cv[3]=c0.w;
      cv[4]=c1.x;cv[5]=c1.y;cv[6]=c1.z;cv[7]=c1.w;
      cv[8]=c2.x;cv[9]=c2.y;cv[10]=c2.z;cv[11]=c2.w;
      cv[12]=c3.x;cv[13]=c3.y;cv[14]=c3.z;cv[15]=c3.w;
      #pragma unroll
      for (int t=0;t<16;t++){
        float a = cv[t]*w1;
        if (t > 0)  a += cv[t-1]*w0;
        if (t < 15) a += cv[t+1]*w2;
        acc[t] += a;
      }
    }
    float m = acc[0];
    #pragma unroll
    for (int t=1;t<16;t++) m = fmaxf(m, acc[t]);
    xr[300 + oc] = fmaxf(m, 0.0f);
  }
  if (tid < 64){
    int d = tid;
    xr[428 + d] = postag_table[postag_in[s]*64 + d];
    xr[492 + d] = position_table[pos_in[s]*64 + d];
    xr[556 + d] = position_table[dep_in[s]*64 + d];
  }
}

// ---------------- fp32 GEMM tile body ----------------
// agentc=1: C stored with agent-scope stores (cross-XCD visible within kernel)
__device__ __forceinline__ void gemm_tile(
    const float* __restrict__ x, const float* __restrict__ Bm,
    const float* __restrict__ bias, float* __restrict__ C,
    int N, int K, int amode, int bx, int by, int tid,
    float (*As)[64], float (*Bs)[64], int agentc)
{
  int bn = bx*64, bm = by*64;
  int lane = tid & 63, kg = tid >> 6;     // kg 0..3, each loads 5 k
  int tx = tid & 15, ty = tid >> 4;       // 16x16, micro 4x4
  float acc[4][4] = {{0.f}};
  for (int k0 = 0; k0 < K; k0 += 20){
    #pragma unroll
    for (int kk=0; kk<5; kk++){
      int k = kg*5 + kk;
      float av;
      if (amode == 0){
        av = x[(size_t)(bm+lane)*DX + k0 + k];
      } else {
        int kc = k0 + k;
        int d  = kc/3;
        int sh = kc - d*3 - 1;
        int row = bm + lane + sh;
        av = (row >= 0 && row < SEQ) ? x[(size_t)row*DX + d] : 0.0f;
      }
      As[k][lane] = av;
      Bs[k][lane] = (amode==0) ? Bm[(size_t)(k0+k)*N + bn + lane]
                               : Bm[(size_t)(bn+lane)*K + k0 + k];
    }
    __syncthreads();
    #pragma unroll
    for (int k=0;k<20;k++){
      float4 a = *(const float4*)&As[k][ty<<2];
      float4 b = *(const float4*)&Bs[k][tx<<2];
      acc[0][0]+=a.x*b.x; acc[0][1]+=a.x*b.y; acc[0][2]+=a.x*b.z; acc[0][3]+=a.x*b.w;
      acc[1][0]+=a.y*b.x; acc[1][1]+=a.y*b.y; acc[1][2]+=a.y*b.z; acc[1][3]+=a.y*b.w;
      acc[2][0]+=a.z*b.x; acc[2][1]+=a.z*b.y; acc[2][2]+=a.z*b.z; acc[2][3]+=a.z*b.w;
      acc[3][0]+=a.w*b.x; acc[3][1]+=a.w*b.y; acc[3][2]+=a.w*b.z; acc[3][3]+=a.w*b.w;
    }
    __syncthreads();
  }
  float4 bb;
  bb.x = bias[bn+(tx<<2)+0]; bb.y = bias[bn+(tx<<2)+1];
  bb.z = bias[bn+(tx<<2)+2]; bb.w = bias[bn+(tx<<2)+3];
  #pragma unroll
  for (int i=0;i<4;i++){
    int row = bm + (ty<<2) + i;
    float v0 = acc[i][0]+bb.x, v1 = acc[i][1]+bb.y, v2 = acc[i][2]+bb.z, v3 = acc[i][3]+bb.w;
    if (agentc){
      float* p = &C[(size_t)row*N + bn + (tx<<2)];
      __hip_atomic_store(p+0, v0, __ATOMIC_RELAXED, __HIP_MEMORY_SCOPE_AGENT);
      __hip_atomic_store(p+1, v1, __ATOMIC_RELAXED, __HIP_MEMORY_SCOPE_AGENT);
      __hip_atomic_store(p+2, v2, __ATOMIC_RELAXED, __HIP_MEMORY_SCOPE_AGENT);
      __hip_atomic_store(p+3, v3, __ATOMIC_RELAXED, __HIP_MEMORY_SCOPE_AGENT);
    } else {
      float4 o; o.x=v0; o.y=v1; o.z=v2; o.w=v3;
      *(float4*)&C[(size_t)row*N + bn + (tx<<2)] = o;
    }
  }
}

// ---------------- global max over tokens for sent conv (two-stage) --------
__global__ __launch_bounds__(256) void k_gmax1(const float* __restrict__ scnn, float* __restrict__ part){
  int b = blockIdx.x, c = threadIdx.x;
  float m = -3.0e38f;
  for (int s = b*64; s < b*64 + 64; s++) m = fmaxf(m, scnn[(size_t)s*256 + c]);
  part[b*256 + c] = m;
}
__global__ __launch_bounds__(256) void k_gmax2(const float* __restrict__ part, float* __restrict__ gcnn){
  int c = threadIdx.x;
  float m = -3.0e38f;
  for (int b=0; b<16; b++) m = fmaxf(m, part[b*256 + c]);
  gcnn[c] = m;
}

struct RGemm {
  const float* B[4];
  const float* bias[4];
  float*       C[4];
  int          N[4];
};

// ---------------- persistent recurrent kernel + ALL folded GEMMs ----------
// 294 blocks x 256 threads. __launch_bounds__(256,1): compiler free to use
// up to 512 VGPR (workers need 192 for register weights — R11's (256,2)
// capped at 128 and spilled, tripling runtime). Hardware still fits 2
// blocks/CU at 192 VGPR; co-residency is NOT required for progress anyway
// (GEMM producers never wait; workers occupy only 6 CUs while producers
// stream through the remaining 250, retire, and free space).
//   bid 0..3    tree-LSTM slices (LLC dataflow exchange)
//   bid 4,5     fwd/bwd LSTM
//   bid 6..261  input GEMM workers: 2 tiles each of {xg_f,xg_b,xiou,xf}
//               (z1 in REVERSE row order for the bwd LSTM); C agent-scope;
//               per-(class,rowgroup) counter released per tile. Consumers
//               gate via watermark (poll only at group boundaries).
//   bid 262..293 conv GEMM workers (3 tiles each, consumed post-kernel)
__global__ __launch_bounds__(256, 1) void k_recur(
    const float* __restrict__ xg_f, const float* __restrict__ xg_b,
    const float* __restrict__ Wh_f, const float* __restrict__ Wh_b,
    const float* __restrict__ xiou, const float* __restrict__ xf,
    const float* __restrict__ Uiou, const float* __restrict__ Uf,
    const int* __restrict__ order, const int* __restrict__ parent,
    float* __restrict__ hf, float* __restrict__ hb,
    float* tree_h, float* iou_acc, float* fcsum,
    const float* __restrict__ x, RGemm rg_args,
    const float* __restrict__ wcnn_w, const float* __restrict__ wcnn_b,
    const float* __restrict__ scnn_w, const float* __restrict__ scnn_b,
    float* __restrict__ lcnn, float* __restrict__ scnn,
    int* cnt)
{
  int bid = blockIdx.x;
  int tid = threadIdx.x;

  if (bid >= 262){
    // ---------- conv GEMM tiles (im2row, K=1860): 3 tiles per block -------
    __shared__ __align__(16) float As[20][64];
    __shared__ __align__(16) float Bs[20][64];
    int j = bid - 262;
    for (int s=0;s<3;s++){
      int tn = j*3 + s;
      if (tn < 32) gemm_tile(x, wcnn_w, wcnn_b, lcnn, 128, 1860, 1, tn&1, tn>>1, tid, As, Bs, 0);
      else { int t2 = tn-32; gemm_tile(x, scnn_w, scnn_b, scnn, 256, 1860, 1, t2&3, t2>>2, tid, As, Bs, 0); }
      __syncthreads();
    }
    return;
  }

  if (bid >= 6){
    // ---------- input GEMM tiles (K=620): 2 tiles per block ----------
    __shared__ __align__(16) float As[20][64];
    __shared__ __align__(16) float Bs[20][64];
    int j = bid - 6;
    for (int s=0;s<2;s++){
      int T = j*2 + s;                 // 0..511, k-chunk ordered
      int k = T>>5, r = T&31;
      int z, by, bn;
      if (r < 8)       { z=0; by=k;    bn=r;    }
      else if (r < 16) { z=1; by=15-k; bn=r-8;  }   // bwd LSTM rows first
      else if (r < 28) { z=2; by=k;    bn=r-16; }
      else             { z=3; by=k;    bn=r-28; }
      gemm_tile(x, rg_args.B[z], rg_args.bias[z], rg_args.C[z], rg_args.N[z],
                620, 0, bn, by, tid, As, Bs, 1);
      __syncthreads();   // drain all waves' C stores before releasing counter
      if (tid == 0)
        __hip_atomic_fetch_add(&cnt[z*16 + by], 1, __ATOMIC_RELEASE, __HIP_MEMORY_SCOPE_AGENT);
      __syncthreads();
    }
    return;
  }

  if (bid >= 4){
    // ---------- BiLSTM: thread = (colgrp 0..127, rowgrp 0..1) ----------
    const float* xg  = (bid == 4) ? xg_f : xg_b;
    const float* Wh  = (bid == 4) ? Wh_f : Wh_b;
    float* hout      = (bid == 4) ? hf : hb;
    int zc = (bid == 4) ? 0 : 1;
    int cg = tid >> 1, rg = tid & 1;          // 4 cols, 64 rows each
    float4 w[4][16];
    #pragma unroll
    for (int cc=0;cc<4;cc++){
      int col = cg*4 + cc;
      #pragma unroll
      for (int r4=0;r4<16;r4++){
        int row = rg*64 + r4*4;
        w[cc][r4].x = Wh[(size_t)(row+0)*512 + col];
        w[cc][r4].y = Wh[(size_t)(row+1)*512 + col];
        w[cc][r4].z = Wh[(size_t)(row+2)*512 + col];
        w[cc][r4].w = Wh[(size_t)(row+3)*512 + col];
      }
    }
    #pragma unroll
    for (int cc=0;cc<4;cc++)
      #pragma unroll
      for (int r4=0;r4<16;r4++)
        asm volatile("" : "+v"(w[cc][r4].x), "+v"(w[cc][r4].y), "+v"(w[cc][r4].z), "+v"(w[cc][r4].w));

    __shared__ __align__(16) float lhl[BIH];
    __shared__ float lcst[BIH];
    __shared__ float gl[512];
    if (tid < BIH){ lhl[tid] = 0.f; lcst[tid] = 0.f; }
    __syncthreads();
    const float4* lhl4 = (const float4*)lhl;

    // watermark over xg row-groups (fwd ascending, bwd descending)
    int Wm = (bid == 4) ? -1 : 16;
    {
      int n0 = (bid == 4) ? 0 : (SEQ-1);
      int g0 = n0 >> 6;
      if (bid == 4){
        for (int g = Wm+1; g <= g0; g++)
          while (__hip_atomic_load(&cnt[zc*16+g], __ATOMIC_ACQUIRE, __HIP_MEMORY_SCOPE_AGENT) < 8)
            __builtin_amdgcn_s_sleep(8);
      } else {
        for (int g = Wm-1; g >= g0; g--)
          while (__hip_atomic_load(&cnt[zc*16+g], __ATOMIC_ACQUIRE, __HIP_MEMORY_SCOPE_AGENT) < 8)
            __builtin_amdgcn_s_sleep(8);
      }
      Wm = g0;
    }
    float4 nxg4 = make_float4(0.f,0.f,0.f,0.f);
    if (rg == 0){
      int n0 = (bid == 4) ? 0 : (SEQ-1);
      nxg4 = *(const float4*)&xg[(size_t)n0*512 + cg*4];
    }
    for (int st=0; st<SEQ; st++){
      int n = (bid == 4) ? st : (SEQ-1-st);
      float4 xg4 = nxg4;
      if (st+1 < SEQ){
        int n1 = (bid == 4) ? (st+1) : (SEQ-2-st);
        int g1 = n1 >> 6;
        if (bid == 4){
          if (g1 > Wm){
            for (int g = Wm+1; g <= g1; g++)
              while (__hip_atomic_load(&cnt[zc*16+g], __ATOMIC_ACQUIRE, __HIP_MEMORY_SCOPE_AGENT) < 8)
                __builtin_amdgcn_s_sleep(8);
            Wm = g1;
          }
        } else {
          if (g1 < Wm){
            for (int g = Wm-1; g >= g1; g--)
              while (__hip_atomic_load(&cnt[zc*16+g], __ATOMIC_ACQUIRE, __HIP_MEMORY_SCOPE_AGENT) < 8)
                __builtin_amdgcn_s_sleep(8);
            Wm = g1;
          }
        }
        if (rg == 0) nxg4 = *(const float4*)&xg[(size_t)n1*512 + cg*4];
      }
      float acc[4] = {0.f,0.f,0.f,0.f};
      #pragma unroll
      for (int r4=0;r4<16;r4++){
        float4 h4 = lhl4[rg*16 + r4];
        #pragma unroll
        for (int cc=0;cc<4;cc++)
          acc[cc] += h4.x*w[cc][r4].x + h4.y*w[cc][r4].y + h4.z*w[cc][r4].z + h4.w*w[cc][r4].w;
      }
      #pragma unroll
      for (int cc=0;cc<4;cc++) acc[cc] += __shfl_xor(acc[cc], 1);
      if (rg == 0){
        float4 o = make_float4(acc[0]+xg4.x, acc[1]+xg4.y, acc[2]+xg4.z, acc[3]+xg4.w);
        *(float4*)&gl[cg*4] = o;
      }
      __syncthreads();   // B1: gates ready
      if (tid < BIH){
        float gi = gl[tid], gf = gl[BIH+tid], gg = gl[2*BIH+tid], go = gl[3*BIH+tid];
        float c = sig_f(gf)*lcst[tid] + sig_f(gi)*tanh_f(gg);
        float h = sig_f(go)*tanh_f(c);
        lcst[tid] = c;
        lhl[tid] = h;
        hout[(size_t)n*BIH + tid] = h;
      }
      __syncthreads();   // B2: lhl ready for next step
    }
    return;
  }

  // ---------- tree-LSTM: 64 units per block ----------
  int blk = bid;
  int cg = tid >> 3, rg = tid & 7;
  int ulo = blk*64;
  float4 w[8][8];   // w[cc][r4]: col cg*8+cc, rows rg*32 + 4*r4 ..+3
  #pragma unroll
  for (int cc=0;cc<8;cc++){
    int c = cg*8 + cc;
    const float* Wsrc; size_t stride; int gcol;
    if (c < 192){ Wsrc = Uiou; stride = 768; gcol = (c>>6)*TLH + ulo + (c&63); }
    else        { Wsrc = Uf;   stride = 256; gcol = ulo + (c-192); }
    #pragma unroll
    for (int r4=0;r4<8;r4++){
      int row = rg*32 + r4*4;
      w[cc][r4].x = Wsrc[(size_t)(row+0)*stride + gcol];
      w[cc][r4].y = Wsrc[(size_t)(row+1)*stride + gcol];
      w[cc][r4].z = Wsrc[(size_t)(row+2)*stride + gcol];
      w[cc][r4].w = Wsrc[(size_t)(row+3)*stride + gcol];
    }
  }
  #pragma unroll
  for (int cc=0;cc<8;cc++)
    #pragma unroll
    for (int r4=0;r4<8;r4++)
      asm volatile("" : "+v"(w[cc][r4].x), "+v"(w[cc][r4].y), "+v"(w[cc][r4].z), "+v"(w[cc][r4].w));

  __shared__ __align__(16) float hl[TLH];      // XOR-swizzled float4 slots
  __shared__ float colsum[TLH];
  __shared__ float cprev[64];
  __shared__ int ord_l[SEQ];
  __shared__ int par_l[SEQ];
  for (int i=tid; i<SEQ; i+=256){ ord_l[i] = order[i]; par_l[i] = parent[i]; }
  __syncthreads();
  const float4* hl4 = (const float4*)hl;

  // watermark over xiou (z2, 12 tiles/group) and xf (z3, 4 tiles/group)
  int Wm = -1;
  float nxi=0.f, nxo=0.f, nxu=0.f, nxf=0.f;
  if (tid < 64){
    int n0 = ord_l[0];
    int need = n0 >> 6;
    for (int g = 0; g <= need; g++){
      while (__hip_atomic_load(&cnt[32+g], __ATOMIC_ACQUIRE, __HIP_MEMORY_SCOPE_AGENT) < 12)
        __builtin_amdgcn_s_sleep(8);
      while (__hip_atomic_load(&cnt[48+g], __ATOMIC_ACQUIRE, __HIP_MEMORY_SCOPE_AGENT) < 4)
        __builtin_amdgcn_s_sleep(8);
    }
    Wm = need;
    int uu = ulo + tid;
    nxi = xiou[(size_t)n0*768 + uu];
    nxo = xiou[(size_t)n0*768 + 256 + uu];
    nxu = xiou[(size_t)n0*768 + 512 + uu];
  }

  for (int t=0; t<SEQ; t++){
    int n  = ord_l[t];
    int m  = (t > 0) ? ord_l[t-1] : 0;
    int pp = (t > 0) ? par_l[m] : -1;
    bool ppeq = (pp == n);

    // consume prefetched x rows; issue next step's prefetch; load accumulators
    float xi=nxi, xo=nxo, xu=nxu, xfv=nxf;
    float ac_i=0.f, ac_o=0.f, ac_u=0.f, fcn=0.f;
    float po_i=0.f, po_o=0.f, po_u=0.f, po_f=0.f;
    if (tid < 64){
      int uu = ulo + tid;
      if (t+1 < SEQ){
        int n1 = ord_l[t+1];
        int pr = par_l[n];                 // pp(t+1) = parent(n)
        int need = n1 >> 6;
        if (pr < SEQ && (pr>>6) > need) need = pr>>6;
        if (need > Wm){
          for (int g = Wm+1; g <= need; g++){
            while (__hip_atomic_load(&cnt[32+g], __ATOMIC_ACQUIRE, __HIP_MEMORY_SCOPE_AGENT) < 12)
              __builtin_amdgcn_s_sleep(8);
            while (__hip_atomic_load(&cnt[48+g], __ATOMIC_ACQUIRE, __HIP_MEMORY_SCOPE_AGENT) < 4)
              __builtin_amdgcn_s_sleep(8);
          }
          Wm = need;
        }
        nxi = xiou[(size_t)n1*768 + uu];
        nxo = xiou[(size_t)n1*768 + 256 + uu];
        nxu = xiou[(size_t)n1*768 + 512 + uu];
        nxf = xf[(size_t)pr*256 + uu];
      }
      ac_i = iou_acc[(size_t)n*768 + uu];
      ac_o = iou_acc[(size_t)n*768 + 256 + uu];
      ac_u = iou_acc[(size_t)n*768 + 512 + uu];
      fcn  = fcsum[(size_t)n*256 + uu];
      if (t > 0 && !ppeq){
        po_i = iou_acc[(size_t)pp*768 + uu];
        po_o = iou_acc[(size_t)pp*768 + 256 + uu];
        po_u = iou_acc[(size_t)pp*768 + 512 + uu];
        po_f = fcsum[(size_t)pp*256 + uu];
      }
    }

    // matvec over h(prev node): 8 swizzled b128 reads, 256 FMAs, shfl reduce
    if (t > 0){
      float acc[8] = {0.f,0.f,0.f,0.f,0.f,0.f,0.f,0.f};
      int base = rg << 3;
      #pragma unroll
      for (int r4=0;r4<8;r4++){
        float4 h4 = hl4[base + (r4 ^ rg)];
        #pragma unroll
        for (int cc=0;cc<8;cc++)
          acc[cc] += h4.x*w[cc][r4].x + h4.y*w[cc][r4].y + h4.z*w[cc][r4].z + h4.w*w[cc][r4].w;
      }
      #pragma unroll
      for (int cc=0;cc<8;cc++){
        acc[cc] += __shfl_xor(acc[cc], 1);
        acc[cc] += __shfl_xor(acc[cc], 2);
        acc[cc] += __shfl_xor(acc[cc], 4);
      }
      if (rg == 0){
        *(float4*)&colsum[cg*8]     = make_float4(acc[0], acc[1], acc[2], acc[3]);
        *(float4*)&colsum[cg*8 + 4] = make_float4(acc[4], acc[5], acc[6], acc[7]);
      }
    }
    __syncthreads();   // B1: colsum ready

    if (tid < 64){
      // fused accumulator-update + cell for unit ulo+tid; publish h (AGENT)
      int uu = ulo + tid;
      float ai = ac_i, ao = ac_o, au = ac_u, fcs = fcn;
      if (t > 0){
        float vi = colsum[tid], vo = colsum[64+tid], vuu = colsum[128+tid], vf = colsum[192+tid];
        float fg  = sig_f(xfv + vf);
        float fcc = fg * cprev[tid];
        if (ppeq){
          ai += vi; ao += vo; au += vuu; fcs += fcc;
        } else {
          iou_acc[(size_t)pp*768 + uu]       = po_i + vi;
          iou_acc[(size_t)pp*768 + 256 + uu] = po_o + vo;
          iou_acc[(size_t)pp*768 + 512 + uu] = po_u + vuu;
          fcsum[(size_t)pp*256 + uu]         = po_f + fcc;
        }
      }
      float cc = sig_f(xi + ai)*tanh_f(xu + au) + fcs;
      float hh = sig_f(xo + ao)*tanh_f(cc);
      cprev[tid] = cc;
      int s = uu >> 2;
      hl[physslot(s)*4 + (uu & 3)] = hh;
      __hip_atomic_store(&tree_h[(size_t)n*TLH + uu], hh, __ATOMIC_RELAXED, __HIP_MEMORY_SCOPE_AGENT);
    } else {
      // gather foreign 192 floats: 192 PARALLEL single-dword AGENT pollers
      int p  = tid - 64;
      int fi = (p < ulo) ? p : p + 64;   // skip own 64 units
      const unsigned* tp = (const unsigned*)(tree_h + (size_t)n*TLH + fi);
      unsigned v = __hip_atomic_load(tp, __ATOMIC_RELAXED, __HIP_MEMORY_SCOPE_AGENT);
      while (v == SENT){
        __builtin_amdgcn_s_sleep(1);
        v = __hip_atomic_load(tp, __ATOMIC_RELAXED, __HIP_MEMORY_SCOPE_AGENT);
      }
      hl[physslot(fi>>2)*4 + (fi&3)] = __uint_as_float(v);
    }
    __syncthreads();   // B2: hl(n) complete for next step's matvec
  }
}

// ---------------- assemble SE + emissions + relations ----------------
__global__ __launch_bounds__(256) void k_assemble(
    const float* __restrict__ hf, const float* __restrict__ hb,
    const float* __restrict__ lcnn, const float* __restrict__ tree_h,
    const float* __restrict__ gcnn,
    const float* __restrict__ crf_w, const float* __restrict__ crf_b,
    const float* __restrict__ rel_w, const float* __restrict__ rel_b,
    const int* __restrict__ ptk,
    float* __restrict__ se_out, float* __restrict__ emis, float* __restrict__ rel_out)
{
  int s = blockIdx.x, tid = threadIdx.x;
  int p = ptk[0];
  __shared__ float se[1536];
  for (int d = tid; d < 1536; d += 256){
    float v;
    if      (d < 128)  v = hf[(size_t)s*128 + d];
    else if (d < 256)  v = hb[(size_t)s*128 + d-128];
    else if (d < 384)  v = lcnn[(size_t)s*128 + d-256];
    else if (d < 640)  v = tree_h[(size_t)s*256 + d-384];
    else if (d < 768)  v = hf[(size_t)p*128 + d-640];
    else if (d < 896)  v = hb[(size_t)p*128 + d-768];
    else if (d < 1024) v = lcnn[(size_t)p*128 + d-896];
    else if (d < 1280) v = tree_h[(size_t)p*256 + d-1024];
    else               v = gcnn[d-1280];
    se[d] = v;
    se_out[(size_t)s*1536 + d] = v;
  }
  __syncthreads();
  int o = tid >> 3, l = tid & 7;   // 32 outputs x 8 lanes
  const float* W = (o < 16) ? crf_w : rel_w;
  int oc = (o < 16) ? o : (o - 16);
  float a = 0.f;
  for (int k = l; k < 1536; k += 8) a += se[k]*W[(size_t)k*16 + oc];
  for (int off = 4; off; off >>= 1) a += __shfl_down(a, off, 8);
  if (l == 0){
    if (o < 16) emis[(size_t)s*16 + o] = a + crf_b[o];
    else        rel_out[(size_t)s*16 + oc] = sig_f(a + rel_b[oc]);
  }
}

// ---------------- entity type ----------------
__global__ __launch_bounds__(256) void k_entity(
    const float* __restrict__ hf, const float* __restrict__ hb,
    const float* __restrict__ lcnn, const float* __restrict__ tree_h,
    const float* __restrict__ gcnn,
    const float* __restrict__ et_w, const float* __restrict__ et_b,
    const int* __restrict__ ptk, float* __restrict__ out_et)
{
  __shared__ float ov[896];
  __shared__ float lg[8];
  int tid = threadIdx.x;
  int p = ptk[0];
  for (int d = tid; d < 896; d += 256){
    float v;
    if      (d < 256) v = gcnn[d];
    else if (d < 384) v = hf[(size_t)p*128 + d-256];
    else if (d < 512) v = hb[(size_t)p*128 + d-384];
    else if (d < 640) v = lcnn[(size_t)p*128 + d-512];
    else              v = tree_h[(size_t)p*256 + d-640];
    ov[d] = v;
  }
  __syncthreads();
  int o = tid >> 5, l = tid & 31;
  float a = 0.f;
  for (int k = l; k < 896; k += 32) a += ov[k]*et_w[(size_t)k*8 + o];
  for (int off = 16; off; off >>= 1) a += __shfl_down(a, off, 32);
  if (l == 0) lg[o] = a + et_b[o];
  __syncthreads();
  if (tid == 0){
    float mx = lg[0];
    for (int i=1;i<8;i++) mx = fmaxf(mx, lg[i]);
    float e[8], sum = 0.f;
    for (int i=0;i<8;i++){ e[i] = __expf(lg[i]-mx); sum += e[i]; }
    for (int i=0;i<8;i++) out_et[i] = e[i]/sum;
  }
}

// ---------------- viterbi: single wave, barrier-free ----------------
__global__ __launch_bounds__(64) void k_viterbi(
    const float* __restrict__ emis, const float* __restrict__ trans, float* __restrict__ out_e)
{
  __shared__ __align__(16) float ring[64][16];
  __shared__ unsigned char ptrs[1023*16];
  __shared__ float scL[16];
  int l = threadIdx.x;
  int j = l >> 2, iq = l & 3;
  float tr0 = trans[(iq*4+0)*16 + j];
  float tr1 = trans[(iq*4+1)*16 + j];
  float tr2 = trans[(iq*4+2)*16 + j];
  float tr3 = trans[(iq*4+3)*16 + j];
  {
    const float* src = &emis[(size_t)l*16];
    float4 a = *(const float4*)(src+0), b = *(const float4*)(src+4);
    float4 c = *(const float4*)(src+8), d = *(const float4*)(src+12);
    *(float4*)&ring[l][0] = a;  *(float4*)&ring[l][4] = b;
    *(float4*)&ring[l][8] = c;  *(float4*)&ring[l][12] = d;
  }
  float cur = ring[0][j];
  float sc0 = __shfl(cur, (iq*4+0)<<2, 64);
  float sc1 = __shfl(cur, (iq*4+1)<<2, 64);
  float sc2 = __shfl(cur, (iq*4+2)<<2, 64);
  float sc3 = __shfl(cur, (iq*4+3)<<2, 64);
  float myfinal = cur;
  for (int t=1; t<1024; t++){
    if ((t & 63) == 0){
      const float* src = &emis[(size_t)(t+l)*16];
      float4 a = *(const float4*)(src+0), b = *(const float4*)(src+4);
      float4 c = *(const float4*)(src+8), d = *(const float4*)(src+12);
      int rr = (t+l) & 63;
      *(float4*)&ring[rr][0] = a;  *(float4*)&ring[rr][4] = b;
      *(float4*)&ring[rr][8] = c;  *(float4*)&ring[rr][12] = d;
    }
    float v0 = sc0 + tr0, v1 = sc1 + tr1, v2 = sc2 + tr2, v3 = sc3 + tr3;
    float best = v0; int barg = iq*4;
    if (v1 > best){ best = v1; barg = iq*4+1; }
    if (v2 > best){ best = v2; barg = iq*4+2; }
    if (v3 > best){ best = v3; barg = iq*4+3; }
    float ob = __shfl_down(best, 1, 4); int oa = __shfl_down(barg, 1, 4);
    if (ob > best){ best = ob; barg = oa; }
    ob = __shfl_down(best, 2, 4); oa = __shfl_down(barg, 2, 4);
    if (ob > best){ best = ob; barg = oa; }
    float ns = 0.f;
    if (iq == 0){
      ns = best + ring[t & 63][j];
      ptrs[(t-1)*16 + j] = (unsigned char)barg;
      myfinal = ns;
    }
    sc0 = __shfl(ns, (iq*4+0)<<2, 64);
    sc1 = __shfl(ns, (iq*4+1)<<2, 64);
    sc2 = __shfl(ns, (iq*4+2)<<2, 64);
    sc3 = __shfl(ns, (iq*4+3)<<2, 64);
  }
  if (iq == 0) scL[j] = myfinal;
  if (l == 0){
    float b = scL[0]; int last = 0;
    #pragma unroll
    for (int i=1;i<16;i++){ if (scL[i] > b){ b = scL[i]; last = i; } }
    out_e[1023] = (float)last;
    int cur2 = last;
    for (int t=1022; t>=0; t--){ cur2 = (int)ptrs[t*16 + cur2]; out_e[t] = (float)cur2; }
  }
}

extern "C" void kernel_launch(void* const* d_in, const int* in_sizes, int n_in,
                              void* d_out, int out_size, void* d_ws, size_t ws_size,
                              hipStream_t stream)
{
  (void)in_sizes; (void)n_in; (void)out_size; (void)ws_size;
  const int*   wi         = (const int*)d_in[0];
  const int*   ci         = (const int*)d_in[1];
  const int*   postag_in  = (const int*)d_in[2];
  const int*   dep_in     = (const int*)d_in[3];
  const int*   pos_in     = (const int*)d_in[4];
  const int*   order      = (const int*)d_in[5];
  const int*   parent     = (const int*)d_in[6];
  const int*   ptk        = (const int*)d_in[7];
  const float* word_table = (const float*)d_in[8];
  const float* char_table = (const float*)d_in[9];
  const float* ccw        = (const float*)d_in[10];
  const float* ccb        = (const float*)d_in[11];
  const float* postag_tab = (const float*)d_in[12];
  const float* pos_tab    = (const float*)d_in[13];
  const float* Wx_f       = (const float*)d_in[14];
  const float* Wh_f       = (const float*)d_in[15];
  const float* b_f        = (const float*)d_in[16];
  const float* Wx_b       = (const float*)d_in[17];
  const float* Wh_b       = (const float*)d_in[18];
  const float* b_b        = (const float*)d_in[19];
  const float* wcnn_w     = (const float*)d_in[20];
  const float* wcnn_b     = (const float*)d_in[21];
  const float* Wiou       = (const float*)d_in[22];
  const float* Uiou       = (const float*)d_in[23];
  const float* biou       = (const float*)d_in[24];
  const float* Wf_t       = (const float*)d_in[25];
  const float* Uf_t       = (const float*)d_in[26];
  const float* bf_t       = (const float*)d_in[27];
  const float* scnn_w     = (const float*)d_in[28];
  const float* scnn_b     = (const float*)d_in[29];
  const float* et_w       = (const float*)d_in[30];
  const float* et_b       = (const float*)d_in[31];
  const float* crf_w      = (const float*)d_in[32];
  const float* crf_b      = (const float*)d_in[33];
  const float* crf_trans  = (const float*)d_in[34];
  const float* rel_w      = (const float*)d_in[35];
  const float* rel_b      = (const float*)d_in[36];

  float* ws = (float*)d_ws;
  float* x      = ws + O_X;
  float* xg_f   = ws + O_XGF;
  float* xg_b   = ws + O_XGB;
  float* xiou   = ws + O_XIOU;
  float* xf     = ws + O_XF;
  float* lcnn   = ws + O_LCNN;
  float* scnn   = ws + O_SCNN;
  float* part   = ws + O_PART;
  float* gcnn   = ws + O_GCNN;
  float* hf     = ws + O_HF;
  float* hb     = ws + O_HB;
  float* tree_h = ws + O_TREEH;
  float* iou_acc= ws + O_IOUA;
  float* fcsum  = ws + O_FCSUM;
  float* emis   = ws + O_EMIS;
  int*   cnt    = (int*)(ws + O_CNT);

  float* outF     = (float*)d_out;
  float* se_out   = outF;                       // 1024*1536
  float* et_out   = outF + 1572864;             // 8
  float* ent_out  = outF + 1572872;             // 1024
  float* rel_out  = outF + 1573896;             // 1024*16

  // per-launch init: zero accumulators + xf pad rows + counters; sentinel tree_h
  hipMemsetAsync(xf, 0, (size_t)1025*256*sizeof(float), stream);
  hipMemsetAsync(iou_acc, 0, ((size_t)1025*768 + 1025*256)*sizeof(float), stream);
  hipMemsetAsync(tree_h, 0xFF, (size_t)1024*256*sizeof(float), stream);
  hipMemsetAsync(cnt, 0, 256, stream);

  k_embed<<<SEQ, 128, 0, stream>>>(wi, ci, postag_in, dep_in, pos_in,
                                   word_table, char_table, ccw, ccb,
                                   postag_tab, pos_tab, x);

  RGemm rga;
  rga.B[0]=Wx_f;  rga.bias[0]=b_f;   rga.C[0]=xg_f; rga.N[0]=512;
  rga.B[1]=Wx_b;  rga.bias[1]=b_b;   rga.C[1]=xg_b; rga.N[1]=512;
  rga.B[2]=Wiou;  rga.bias[2]=biou;  rga.C[2]=xiou; rga.N[2]=768;
  rga.B[3]=Wf_t;  rga.bias[3]=bf_t;  rga.C[3]=xf;   rga.N[3]=256;

  // ALL GEMMs folded into k_recur
  k_recur<<<294, 256, 0, stream>>>(xg_f, xg_b, Wh_f, Wh_b, xiou, xf, Uiou, Uf_t,
                                   order, parent, hf, hb, tree_h, iou_acc, fcsum,
                                   x, rga, wcnn_w, wcnn_b, scnn_w, scnn_b, lcnn, scnn,
                                   cnt);

  k_gmax1<<<16, 256, 0, stream>>>(scnn, part);
  k_gmax2<<<1, 256, 0, stream>>>(part, gcnn);

  k_assemble<<<SEQ, 256, 0, stream>>>(hf, hb, lcnn, tree_h, gcnn,
                                      crf_w, crf_b, rel_w, rel_b, ptk,
                                      se_out, emis, rel_out);

  k_entity<<<1, 256, 0, stream>>>(hf, hb, lcnn, tree_h, gcnn, et_w, et_b, ptk, et_out);

  k_viterbi<<<1, 64, 0, stream>>>(emis, crf_trans, ent_out);
}